// Round 6
// baseline (501.264 us; speedup 1.0000x reference)
//
#include <hip/hip_runtime.h>
#include <hip/hip_bf16.h>
#include <stdint.h>
#include <stddef.h>

typedef unsigned short u16;
typedef __attribute__((ext_vector_type(8))) short short8;
typedef __attribute__((ext_vector_type(4))) float f32x4;

#define NB 4
#define NL 1024
#define ND 768
#define NH 12
#define NDH 64

__device__ __forceinline__ u16 f2bf(float f) {
  __hip_bfloat16 h = __float2bfloat16(f);
  return *reinterpret_cast<u16*>(&h);
}
__device__ __forceinline__ float bf2f(u16 u) {
  __hip_bfloat16 h;
  *reinterpret_cast<u16*>(&h) = u;
  return __bfloat162float(h);
}

// async global->LDS, 16B per lane. LDS dest is wave-uniform base; HW adds lane*16.
__device__ __forceinline__ void load16_to_lds(const u16* g, u16* l) {
  __builtin_amdgcn_global_load_lds(
      (__attribute__((address_space(1))) void*)(uintptr_t)g,
      (__attribute__((address_space(3))) void*)(uint32_t)(uintptr_t)l,
      16, 0, 0);
}

// swizzle helpers: XOR 16B-chunk index within 8-chunk (64-elem) groups
__device__ __forceinline__ int swz8(int c, int r) { return (c ^ r) & 7; }
__device__ __forceinline__ int swz16(int c, int r) { return (c & 8) | ((c ^ r) & 7); }
__device__ __forceinline__ int swzT(int c, int r) { return (c & ~7) | ((c ^ r) & 7); }

// ---------------- cast fp32 -> bf16 (vectorized) ----------------
__global__ __launch_bounds__(256) void cast_bf16_kernel(const float* __restrict__ in,
                                                        u16* __restrict__ out, int n4) {
  int i = blockIdx.x * 256 + threadIdx.x;
  int stride = gridDim.x * 256;
  for (; i < n4; i += stride) {
    float4 f = ((const float4*)in)[i];
    ushort4 o;
    o.x = f2bf(f.x); o.y = f2bf(f.y); o.z = f2bf(f.z); o.w = f2bf(f.w);
    ((ushort4*)out)[i] = o;
  }
}

// ---------------- transpose+cast: out[h][c][r] = in[h][r][c], 768x768 per head ----------------
__global__ __launch_bounds__(256) void transpose_cast_kernel(const float* __restrict__ in,
                                                             u16* __restrict__ out) {
  __shared__ float tile[32][33];
  int h = blockIdx.z;
  const float* src = in + (size_t)h * ND * ND;
  u16* dst = out + (size_t)h * ND * ND;
  int c0 = blockIdx.x * 32, r0 = blockIdx.y * 32;
  int tx = threadIdx.x & 31, ty = threadIdx.x >> 5;
#pragma unroll
  for (int i = 0; i < 32; i += 8)
    tile[ty + i][tx] = src[(size_t)(r0 + ty + i) * ND + c0 + tx];
  __syncthreads();
#pragma unroll
  for (int i = 0; i < 32; i += 8)
    dst[(size_t)(c0 + ty + i) * ND + r0 + tx] = f2bf(tile[tx][ty + i]);
}

// ---------------- gemm_bt: C[M,N] = A[M,K] * B[N,K]^T, bf16 in, fp32 acc ----------------
template <bool BF16_OUT, int IT, int JT, int KDIM, int LDC, int BK>
__global__ __launch_bounds__(256) void gemm_bt(
    const u16* __restrict__ A, const u16* __restrict__ Bm, void* __restrict__ Cv,
    long sAb, long sAn, long sAz,
    long sBb, long sBn, long sBz,
    long sCb, long sCn, long sCz,
    int p0) {
  constexpr int MTILE = IT * 32;
  constexpr int NTILE = JT * 32;
  constexpr int CPR = BK / 8;
  constexpr int ACH = MTILE * CPR / 256;
  constexpr int BCH = NTILE * CPR / 256;
  constexpr int KC = BK / 32;
  __shared__ __align__(16) u16 As[MTILE * BK];
  __shared__ __align__(16) u16 Bs[NTILE * BK];

  int id = blockIdx.x + gridDim.x * (blockIdx.y + gridDim.y * blockIdx.z);
  int total = gridDim.x * gridDim.y * gridDim.z;
  int xx, yy, zz;
  if ((total & 7) == 0) {
    int per = total >> 3;
    int wk = (id & 7) * per + (id >> 3);
    xx = wk % gridDim.x;
    int g2 = wk / gridDim.x;
    yy = g2 % gridDim.y;
    zz = g2 / gridDim.y;
  } else {
    xx = blockIdx.x; yy = blockIdx.y; zz = blockIdx.z;
  }

  int g = p0 + zz;
  int b = g / NH, n = g % NH;
  A  += (size_t)b * sAb + (size_t)n * sAn + (size_t)zz * sAz;
  Bm += (size_t)b * sBb + (size_t)n * sBn + (size_t)zz * sBz;
  size_t cOff = (size_t)b * sCb + (size_t)n * sCn + (size_t)zz * sCz;

  int m0 = yy * MTILE, n0 = xx * NTILE;
  int t = threadIdx.x;
  int lane = t & 63, w = t >> 6;
  int row16 = lane & 15, q = lane >> 4;
  int wm = w >> 1, wn = w & 1;
  int rsw = (BK == 32) ? ((row16 >> 1) & 3) : (row16 & 7);

  const u16* gA[ACH];
  const u16* gB[BCH];
#pragma unroll
  for (int u = 0; u < ACH; u++) {
    int c = u * 256 + t;
    int r = c / CPR;
    int sw = (BK == 32) ? ((r >> 1) & 3) : (r & 7);
    int cc = (c & (CPR - 1)) ^ sw;
    gA[u] = A + (size_t)(m0 + r) * KDIM + cc * 8;
  }
#pragma unroll
  for (int u = 0; u < BCH; u++) {
    int c = u * 256 + t;
    int r = c / CPR;
    int sw = (BK == 32) ? ((r >> 1) & 3) : (r & 7);
    int cc = (c & (CPR - 1)) ^ sw;
    gB[u] = Bm + (size_t)(n0 + r) * KDIM + cc * 8;
  }

  f32x4 acc[IT][JT];
#pragma unroll
  for (int i = 0; i < IT; i++)
#pragma unroll
    for (int j = 0; j < JT; j++) acc[i][j] = (f32x4){0.f, 0.f, 0.f, 0.f};

#pragma unroll 1
  for (int k0 = 0; k0 < KDIM; k0 += BK) {
    __syncthreads();
#pragma unroll
    for (int u = 0; u < ACH; u++) {
      load16_to_lds(gA[u], &As[(size_t)(u * 256 + w * 64) * 8]);
      gA[u] += BK;
    }
#pragma unroll
    for (int u = 0; u < BCH; u++) {
      load16_to_lds(gB[u], &Bs[(size_t)(u * 256 + w * 64) * 8]);
      gB[u] += BK;
    }
    __syncthreads();

#pragma unroll
    for (int kc = 0; kc < KC; kc++) {
      int ch = ((kc * 4 + q) ^ rsw) * 8;
      short8 af[IT], bfr[JT];
#pragma unroll
      for (int i = 0; i < IT; i++)
        af[i] = *(const short8*)&As[(wm * (IT * 16) + i * 16 + row16) * BK + ch];
#pragma unroll
      for (int j = 0; j < JT; j++)
        bfr[j] = *(const short8*)&Bs[(wn * (JT * 16) + j * 16 + row16) * BK + ch];
#pragma unroll
      for (int i = 0; i < IT; i++)
#pragma unroll
        for (int j = 0; j < JT; j++)
          acc[i][j] = __builtin_amdgcn_mfma_f32_16x16x32_bf16(af[i], bfr[j], acc[i][j], 0, 0, 0);
    }
  }

#pragma unroll
  for (int i = 0; i < IT; i++) {
    int row = m0 + wm * (IT * 16) + i * 16 + q * 4;
#pragma unroll
    for (int j = 0; j < JT; j++) {
      int col = n0 + wn * (JT * 16) + j * 16 + row16;
#pragma unroll
      for (int r = 0; r < 4; r++) {
        float vv = acc[i][j][r];
        if (BF16_OUT) {
          ((u16*)Cv)[cOff + (size_t)(row + r) * LDC + col] = f2bf(vv);
        } else {
          ((float*)Cv)[cOff + (size_t)(row + r) * LDC + col] = vv;
        }
      }
    }
  }
}

// ---------------- fused scores + softmax + PV ----------------
// Block = (64 T-rows l0, pair z). T tile (64x768 bf16 = 96KB) resident in LDS.
// m-loop over 8 tiles of 128: S = Ts*x^T (BK=64 GEMM, B streamed), exp in-register,
// scatter exp(S) to Ss (C-layout -> A-layout transform via LDS), PV MFMA with a
// ones-column B-frag producing row sums; epilogue divides and stores fp32 out.
// Logits are O(1) (bf16-safe) -> no max subtraction, no online rescale.
// LDS 144KB -> 1 block/CU; grid 16*48=768 = exactly 3 waves of 256 CUs.
__global__ __launch_bounds__(256) void attn_pv_kernel(
    const u16* __restrict__ T, const u16* __restrict__ xb, const u16* __restrict__ V2,
    float* __restrict__ out, int p0) {
  extern __shared__ u16 smem[];
  u16* Ts = smem;                  // 64*768  u16 (96 KB), chunk-swizzled (swzT)
  u16* Bs = smem + 49152;          // 128*64  u16 (16 KB), swz8
  u16* Vs = smem + 57344;          // 64*128  u16 (16 KB), swz16
  u16* Ss = smem + 65536;          // 64*128  u16 (16 KB), swz16

  int id = blockIdx.x + gridDim.x * blockIdx.y;
  int per = (gridDim.x * gridDim.y) >> 3;   // total = 16*c, always %8==0
  int wk = (id & 7) * per + (id >> 3);
  int xx = wk & 15, zz = wk >> 4;

  int g = p0 + zz;
  int b = g / NH, n = g % NH;
  const u16* Tz = T + (size_t)zz * NL * ND + (size_t)xx * 64 * ND;
  const u16* xbb = xb + (size_t)b * NL * ND;
  const u16* Vz = V2 + (size_t)zz * NDH * NL;
  int l0 = xx * 64;

  int t = threadIdx.x;
  int lane = t & 63, w = t >> 6;
  int row16 = lane & 15, q = lane >> 4;
  int wm = w >> 1, wn = w & 1;

  // Phase 0: stage T tile. 64 rows x 96 chunks = 6144 chunks, 24/thread.
#pragma unroll
  for (int u = 0; u < 24; u++) {
    int c = u * 256 + t;
    int r = c / 96, rem = c - r * 96;
    int lg = swzT(rem, r);  // involutive: LDS chunk (r,rem) gets global chunk lg
    load16_to_lds(Tz + (size_t)r * ND + lg * 8, &Ts[(size_t)(u * 256 + w * 64) * 8]);
  }

  // per-thread staging bases
  const u16* bsrc[4];
#pragma unroll
  for (int u = 0; u < 4; u++) {
    int c = u * 256 + t;
    int r = c >> 3, cc = (c & 7) ^ (r & 7);
    bsrc[u] = xbb + (size_t)r * ND + cc * 8;
  }
  const u16* vsrc[4];
#pragma unroll
  for (int u = 0; u < 4; u++) {
    int c = u * 256 + t;
    int r = c >> 4, cc = (c & 15) ^ (r & 7);
    vsrc[u] = Vz + (size_t)r * NL + cc * 8;
  }

  f32x4 acc_o[5];
#pragma unroll
  for (int j = 0; j < 5; j++) acc_o[j] = (f32x4){0.f, 0.f, 0.f, 0.f};

  short8 onesf;
  {
    short val = (row16 == 0) ? (short)0x3F80 : (short)0;
#pragma unroll
    for (int e = 0; e < 8; e++) onesf[e] = val;
  }

#pragma unroll 1
  for (int mt = 0; mt < 8; mt++) {
    int mo = mt * 128;
    __syncthreads();  // prev PV reads of Vs/Ss done
#pragma unroll
    for (int u = 0; u < 4; u++)
      load16_to_lds(vsrc[u] + mo, &Vs[(size_t)(u * 256 + w * 64) * 8]);

    f32x4 acc_s[2][4];
#pragma unroll
    for (int i = 0; i < 2; i++)
#pragma unroll
      for (int j = 0; j < 4; j++) acc_s[i][j] = (f32x4){0.f, 0.f, 0.f, 0.f};

#pragma unroll 1
    for (int kb = 0; kb < 12; kb++) {
      __syncthreads();  // prev iter's Bs frag reads done
#pragma unroll
      for (int u = 0; u < 4; u++)
        load16_to_lds(bsrc[u] + ((size_t)mo * ND + kb * 64), &Bs[(size_t)(u * 256 + w * 64) * 8]);
      __syncthreads();  // vmcnt drained (Vs too on kb==0)

#pragma unroll
      for (int kc = 0; kc < 2; kc++) {
        short8 af[2], bfr[4];
#pragma unroll
        for (int i = 0; i < 2; i++) {
          int l = wm * 32 + i * 16 + row16;
          int ck = kb * 8 + kc * 4 + q;
          af[i] = *(const short8*)&Ts[l * ND + swzT(ck, l) * 8];
        }
#pragma unroll
        for (int j = 0; j < 4; j++) {
          int r = wn * 64 + j * 16 + row16;
          bfr[j] = *(const short8*)&Bs[r * 64 + swz8(kc * 4 + q, r) * 8];
        }
#pragma unroll
        for (int i = 0; i < 2; i++)
#pragma unroll
          for (int j = 0; j < 4; j++)
            acc_s[i][j] = __builtin_amdgcn_mfma_f32_16x16x32_bf16(af[i], bfr[j], acc_s[i][j], 0, 0, 0);
      }
    }

    // exp + scatter to Ss (C-layout -> [l][m] A-layout), bf16
#pragma unroll
    for (int i = 0; i < 2; i++) {
#pragma unroll
      for (int j = 0; j < 4; j++) {
#pragma unroll
        for (int r = 0; r < 4; r++) {
          int l = wm * 32 + i * 16 + q * 4 + r;
          int col = wn * 64 + j * 16 + row16;
          Ss[l * 128 + swz16(col >> 3, l) * 8 + (col & 7)] = f2bf(__expf(acc_s[i][j][r]));
        }
      }
    }
    __syncthreads();  // Ss complete before PV reads

    // PV: each wave handles 16 rows (l = w*16+row16), all 64 dh cols
#pragma unroll
    for (int kk = 0; kk < 4; kk++) {
      int l = w * 16 + row16;
      short8 af = *(const short8*)&Ss[l * 128 + swz16(kk * 4 + q, l) * 8];
      short8 bfr[4];
#pragma unroll
      for (int j = 0; j < 4; j++) {
        int dh = j * 16 + row16;
        bfr[j] = *(const short8*)&Vs[dh * 128 + swz16(kk * 4 + q, dh) * 8];
      }
#pragma unroll
      for (int j = 0; j < 4; j++)
        acc_o[j] = __builtin_amdgcn_mfma_f32_16x16x32_bf16(af, bfr[j], acc_o[j], 0, 0, 0);
      acc_o[4] = __builtin_amdgcn_mfma_f32_16x16x32_bf16(af, onesf, acc_o[4], 0, 0, 0);
    }
  }

  // epilogue: row l = l0 + w*16 + q*4 + r; col dh = j*16 + row16; divide by rowsum
#pragma unroll
  for (int r = 0; r < 4; r++) {
    float sum = __shfl(acc_o[4][r], lane & 48, 64);
    float inv = 1.0f / sum;
    int row = l0 + w * 16 + q * 4 + r;
    float* op = out + ((size_t)b * NL + row) * ND + n * NDH;
#pragma unroll
    for (int j = 0; j < 4; j++)
      op[j * 16 + row16] = acc_o[j][r] * inv;
  }
}

extern "C" void kernel_launch(void* const* d_in, const int* in_sizes, int n_in,
                              void* d_out, int out_size, void* d_ws, size_t ws_size,
                              hipStream_t stream) {
  (void)in_sizes; (void)n_in; (void)out_size;
  const float* x  = (const float*)d_in[0];
  const float* kI = (const float*)d_in[1];
  const float* qI = (const float*)d_in[2];
  const float* vI = (const float*)d_in[3];
  float* out = (float*)d_out;

  size_t off = 0;
  char* wsb = (char*)d_ws;
  auto alloc = [&](size_t bytes) -> char* {
    char* p = wsb + off;
    off += (bytes + 255) & ~(size_t)255;
    return p;
  };
  u16* xb = (u16*)alloc((size_t)NB * NL * ND * 2);   // bf16 x, [b][l][d]
  u16* qT = (u16*)alloc((size_t)NH * ND * ND * 2);   // q^T per head: [n][d][c]
  u16* kT = (u16*)alloc((size_t)NH * ND * ND * 2);   // k^T per head: [n][e][c]
  u16* vb = (u16*)alloc((size_t)NH * NDH * ND * 2);  // bf16 v, [n][dh][d]
  u16* MT = (u16*)alloc((size_t)NH * ND * ND * 2);   // MT[n][e][d] = M[d][e]
  size_t fixedSz = off;
  const size_t perPair = (size_t)NL * ND * 2 + (size_t)NDH * NL * 2;
  int chunk = NB * NH;
  if (fixedSz + (size_t)chunk * perPair > ws_size) {
    size_t avail = ws_size > fixedSz ? ws_size - fixedSz : 0;
    chunk = (int)(avail / perPair);
    if (chunk < 1) chunk = 1;
    if (chunk > NB * NH) chunk = NB * NH;
  }
  u16* T  = (u16*)alloc((size_t)chunk * NL * ND * 2);   // [z][l][e]
  u16* V2 = (u16*)alloc((size_t)chunk * NDH * NL * 2);  // [z][dh][m]

  const long DD  = (long)ND * ND;
  const long LD  = (long)NL * ND;
  const long DHD = (long)NDH * ND;
  const long DHL = (long)NDH * NL;

  // allow 144KB dynamic LDS for the fused kernel (idempotent, capture-safe)
  hipFuncSetAttribute((const void*)attn_pv_kernel,
                      hipFuncAttributeMaxDynamicSharedMemorySize, 147456);

  {
    int n4 = NB * NL * ND / 4;
    cast_bf16_kernel<<<dim3((n4 + 255) / 256), dim3(256), 0, stream>>>(x, xb, n4);
    int n4v = NH * NDH * ND / 4;
    cast_bf16_kernel<<<dim3((n4v + 255) / 256), dim3(256), 0, stream>>>(vI, vb, n4v);
  }
  transpose_cast_kernel<<<dim3(24, 24, NH), dim3(256), 0, stream>>>(qI, qT);
  transpose_cast_kernel<<<dim3(24, 24, NH), dim3(256), 0, stream>>>(kI, kT);

  // MT[n][e][d] = sum_c kT[n][e][c] * qT[n][d][c]   (768x768, K=768)
  gemm_bt<true, 4, 4, 768, ND, 64><<<dim3(6, 6, NH), dim3(256), 0, stream>>>(
      kT, qT, MT,
      0, DD, 0,  0, DD, 0,  0, DD, 0, 0);

  for (int p0 = 0; p0 < NB * NH; p0 += chunk) {
    int c = NB * NH - p0;
    if (c > chunk) c = chunk;
    // V2[z][dh][m] = sum_d vb[n][dh][d] * xb[b][m][d]   (64x1024, K=768), 64x64 tiles
    gemm_bt<true, 2, 2, 768, NL, 64><<<dim3(16, 1, c), dim3(256), 0, stream>>>(
        vb, xb, V2,
        0, DHD, 0,  LD, 0, 0,  0, 0, DHL, p0);
    // T[z][l][e] = sum_d xb[b][l][d] * MT[n][e][d]   (1024x768, K=768)
    gemm_bt<true, 4, 4, 768, ND, 64><<<dim3(6, 8, c), dim3(256), 0, stream>>>(
        xb, MT, T,
        LD, 0, 0,  0, DD, 0,  0, 0, LD, p0);
    // fused scores + softmax + PV -> writes out directly
    attn_pv_kernel<<<dim3(16, c), dim3(256), 147456, stream>>>(T, xb, V2, out, p0);
  }
}

// Round 7
// 318.636 us; speedup vs baseline: 1.5732x; 1.5732x over previous
//
#include <hip/hip_runtime.h>
#include <hip/hip_bf16.h>
#include <stdint.h>
#include <stddef.h>

typedef unsigned short u16;
typedef __attribute__((ext_vector_type(8))) short short8;
typedef __attribute__((ext_vector_type(4))) float f32x4;
typedef __attribute__((ext_vector_type(16))) float f32x16;

#define NB 4
#define NL 1024
#define ND 768
#define NH 12
#define NDH 64

__device__ __forceinline__ u16 f2bf(float f) {
  __hip_bfloat16 h = __float2bfloat16(f);
  return *reinterpret_cast<u16*>(&h);
}
__device__ __forceinline__ float bf2f(u16 u) {
  __hip_bfloat16 h;
  *reinterpret_cast<u16*>(&h) = u;
  return __bfloat162float(h);
}

// async global->LDS, 16B per lane. LDS dest is wave-uniform base; HW adds lane*16.
__device__ __forceinline__ void load16_to_lds(const u16* g, u16* l) {
  __builtin_amdgcn_global_load_lds(
      (__attribute__((address_space(1))) void*)(uintptr_t)g,
      (__attribute__((address_space(3))) void*)(uint32_t)(uintptr_t)l,
      16, 0, 0);
}

// ---------------- cast fp32 -> bf16 (vectorized) ----------------
__global__ __launch_bounds__(256) void cast_bf16_kernel(const float* __restrict__ in,
                                                        u16* __restrict__ out, int n4) {
  int i = blockIdx.x * 256 + threadIdx.x;
  int stride = gridDim.x * 256;
  for (; i < n4; i += stride) {
    float4 f = ((const float4*)in)[i];
    ushort4 o;
    o.x = f2bf(f.x); o.y = f2bf(f.y); o.z = f2bf(f.z); o.w = f2bf(f.w);
    ((ushort4*)out)[i] = o;
  }
}

// ---------------- transpose+cast: out[h][c][r] = in[h][r][c], 768x768 per head ----------------
__global__ __launch_bounds__(256) void transpose_cast_kernel(const float* __restrict__ in,
                                                             u16* __restrict__ out) {
  __shared__ float tile[32][33];
  int h = blockIdx.z;
  const float* src = in + (size_t)h * ND * ND;
  u16* dst = out + (size_t)h * ND * ND;
  int c0 = blockIdx.x * 32, r0 = blockIdx.y * 32;
  int tx = threadIdx.x & 31, ty = threadIdx.x >> 5;
#pragma unroll
  for (int i = 0; i < 32; i += 8)
    tile[ty + i][tx] = src[(size_t)(r0 + ty + i) * ND + c0 + tx];
  __syncthreads();
#pragma unroll
  for (int i = 0; i < 32; i += 8)
    dst[(size_t)(c0 + ty + i) * ND + r0 + tx] = f2bf(tile[tx][ty + i]);
}

// ---------------- gemm_bt: C[M,N] = A[M,K] * B[N,K]^T, bf16 in, fp32 acc ----------------
// 32x32x16 MFMA version. MTILE = IM*64, NTILE = IN*64; 256 threads = 4 waves in 2x2
// wave-tiles of (IM*32)x(IN*32). BK=64 fixed. Per K=32: 8 ds_read_b128 + IM*IN*2 MFMA
// (half the MFMA issue count of the 16x16 variant; 32x32 pipe ~20% better FLOP/cyc).
// A-frag: m=lane&31, k=(lane>>5)*8+e (K-generalized from verified 16x16 layout).
// C/D: col=lane&31, row=(reg&3)+8*(reg>>2)+4*(lane>>5) [m74/m101 verified].
// XCD swizzle: chunk-contiguous work per XCD (id%8 == XCD on MI355X).
// LDS XOR bank swizzle: chunk ^= (row&7) both sides -> every 16-lane phase 2-way (free).
template <bool BF16_OUT, int IM, int IN, int KDIM, int LDC>
__global__ __launch_bounds__(256) void gemm_bt(
    const u16* __restrict__ A, const u16* __restrict__ Bm, void* __restrict__ Cv,
    long sAb, long sAn, long sAz,
    long sBb, long sBn, long sBz,
    long sCb, long sCn, long sCz,
    int p0) {
  constexpr int BK = 64;
  constexpr int MTILE = IM * 64;
  constexpr int NTILE = IN * 64;
  constexpr int CPR = BK / 8;             // 8 chunks of 16B per row
  constexpr int ACH = MTILE * CPR / 256;
  constexpr int BCH = NTILE * CPR / 256;
  __shared__ __align__(16) u16 As[MTILE * BK];
  __shared__ __align__(16) u16 Bs[NTILE * BK];

  int id = blockIdx.x + gridDim.x * (blockIdx.y + gridDim.y * blockIdx.z);
  int total = gridDim.x * gridDim.y * gridDim.z;
  int xx, yy, zz;
  if ((total & 7) == 0) {
    int per = total >> 3;
    int wk = (id & 7) * per + (id >> 3);
    xx = wk % gridDim.x;
    int g2 = wk / gridDim.x;
    yy = g2 % gridDim.y;
    zz = g2 / gridDim.y;
  } else {
    xx = blockIdx.x; yy = blockIdx.y; zz = blockIdx.z;
  }

  int g = p0 + zz;
  int b = g / NH, n = g % NH;
  A  += (size_t)b * sAb + (size_t)n * sAn + (size_t)zz * sAz;
  Bm += (size_t)b * sBb + (size_t)n * sBn + (size_t)zz * sBz;
  size_t cOff = (size_t)b * sCb + (size_t)n * sCn + (size_t)zz * sCz;

  int m0 = yy * MTILE, n0 = xx * NTILE;
  int t = threadIdx.x;
  int lane = t & 63, w = t >> 6;
  int m32 = lane & 31, kg = lane >> 5;
  int wm = w >> 1, wn = w & 1;

  // write-side staging pointers (XOR swizzle), advanced BK elems per K-iter
  const u16* gA[ACH];
  const u16* gB[BCH];
#pragma unroll
  for (int u = 0; u < ACH; u++) {
    int c = u * 256 + t;
    int r = c / CPR;
    int cc = (c & (CPR - 1)) ^ (r & 7);
    gA[u] = A + (size_t)(m0 + r) * KDIM + cc * 8;
  }
#pragma unroll
  for (int u = 0; u < BCH; u++) {
    int c = u * 256 + t;
    int r = c / CPR;
    int cc = (c & (CPR - 1)) ^ (r & 7);
    gB[u] = Bm + (size_t)(n0 + r) * KDIM + cc * 8;
  }

  f32x16 acc[IM][IN];
#pragma unroll
  for (int i = 0; i < IM; i++)
#pragma unroll
    for (int j = 0; j < IN; j++)
#pragma unroll
      for (int r = 0; r < 16; r++) acc[i][j][r] = 0.f;

#pragma unroll 1
  for (int k0 = 0; k0 < KDIM; k0 += BK) {
    __syncthreads();
#pragma unroll
    for (int u = 0; u < ACH; u++) {
      load16_to_lds(gA[u], &As[(size_t)(u * 256 + w * 64) * 8]);
      gA[u] += BK;
    }
#pragma unroll
    for (int u = 0; u < BCH; u++) {
      load16_to_lds(gB[u], &Bs[(size_t)(u * 256 + w * 64) * 8]);
      gB[u] += BK;
    }
    __syncthreads();

#pragma unroll
    for (int kc = 0; kc < 2; kc++) {
      short8 af[IM][2], bfr[IN][2];
#pragma unroll
      for (int i = 0; i < IM; i++) {
        int row = wm * (IM * 32) + i * 32 + m32;
#pragma unroll
        for (int h = 0; h < 2; h++) {
          int ck = (kc * 4 + h * 2 + kg) ^ (row & 7);
          af[i][h] = *(const short8*)&As[row * BK + ck * 8];
        }
      }
#pragma unroll
      for (int j = 0; j < IN; j++) {
        int row = wn * (IN * 32) + j * 32 + m32;
#pragma unroll
        for (int h = 0; h < 2; h++) {
          int ck = (kc * 4 + h * 2 + kg) ^ (row & 7);
          bfr[j][h] = *(const short8*)&Bs[row * BK + ck * 8];
        }
      }
#pragma unroll
      for (int i = 0; i < IM; i++)
#pragma unroll
        for (int j = 0; j < IN; j++) {
          acc[i][j] = __builtin_amdgcn_mfma_f32_32x32x16_bf16(af[i][0], bfr[j][0], acc[i][j], 0, 0, 0);
          acc[i][j] = __builtin_amdgcn_mfma_f32_32x32x16_bf16(af[i][1], bfr[j][1], acc[i][j], 0, 0, 0);
        }
    }
  }

  // epilogue: row = (reg&3) + 8*(reg>>2) + 4*kg; col = m32 (within 32x32 tile)
#pragma unroll
  for (int i = 0; i < IM; i++) {
#pragma unroll
    for (int j = 0; j < IN; j++) {
      int colg = n0 + wn * (IN * 32) + j * 32 + m32;
#pragma unroll
      for (int r = 0; r < 16; r++) {
        int rowg = m0 + wm * (IM * 32) + i * 32 + (r & 3) + 8 * (r >> 2) + 4 * kg;
        float vv = acc[i][j][r];
        if (BF16_OUT) {
          ((u16*)Cv)[cOff + (size_t)rowg * LDC + colg] = f2bf(vv);
        } else {
          ((float*)Cv)[cOff + (size_t)rowg * LDC + colg] = vv;
        }
      }
    }
  }
}

// ---------------- fused softmax + PV ----------------
// out[b][l][n*64+dh] = sum_m exp(Sb[z][l][m]) * V2[z][dh][m] / sum_m exp(Sb[z][l][m])
// Logits are O(1) (bf16-safe) -> no max subtraction, single pass, no rescale.
// 64-row tiles, grid (16,c) = 768 blocks (~3/CU so barrier drains overlap), LDS 32KB.
// 5th B-tile (ones in col 0) makes the MFMA compute row sums; epilogue divides.
__global__ __launch_bounds__(256) void softmax_pv_kernel(
    const u16* __restrict__ Sb, const u16* __restrict__ V2, float* __restrict__ out,
    int p0) {
  __shared__ __align__(16) u16 Ps[64 * 128];  // 16 KB
  __shared__ __align__(16) u16 Vs[64 * 128];  // 16 KB

  int id = blockIdx.x + gridDim.x * blockIdx.y;
  int total = gridDim.x * gridDim.y;
  int xx, zz;
  if ((total & 7) == 0) {
    int per = total >> 3;
    int wk = (id & 7) * per + (id >> 3);
    xx = wk & 15; zz = wk >> 4;
  } else {
    xx = blockIdx.x; zz = blockIdx.y;
  }

  int g = p0 + zz;
  int b = g / NH, n = g % NH;
  const u16* S = Sb + (size_t)zz * NL * NL;
  const u16* V = V2 + (size_t)zz * NDH * NL;

  int l0 = xx * 64;
  int t = threadIdx.x;
  int lane = t & 63, w = t >> 6;
  int row16 = lane & 15, q = lane >> 4;
  int rs = row16 & 7;

  f32x4 acc[5];
#pragma unroll
  for (int j = 0; j < 5; j++) acc[j] = (f32x4){0.f, 0.f, 0.f, 0.f};

  short8 onesf;
  {
    short val = (row16 == 0) ? (short)0x3F80 : (short)0;
#pragma unroll
    for (int e = 0; e < 8; e++) onesf[e] = val;
  }

  // per-thread staging bases (write-side swizzle cc = (c&15)^(r&7))
  const u16* ssrc[4];
  const u16* vsrc[4];
#pragma unroll
  for (int u = 0; u < 4; u++) {
    int c = u * 256 + t;
    int r = c >> 4, cc = (c & 15) ^ (r & 7);
    ssrc[u] = S + (size_t)(l0 + r) * NL + cc * 8;
    vsrc[u] = V + (size_t)r * NL + cc * 8;
  }

#pragma unroll 1
  for (int mt = 0; mt < 8; mt++) {
    int mo = mt * 128;
    __syncthreads();
#pragma unroll
    for (int u = 0; u < 4; u++)
      load16_to_lds(ssrc[u] + mo, &Ps[(size_t)(u * 256 + w * 64) * 8]);
#pragma unroll
    for (int u = 0; u < 4; u++)
      load16_to_lds(vsrc[u] + mo, &Vs[(size_t)(u * 256 + w * 64) * 8]);
    __syncthreads();

#pragma unroll
    for (int kk = 0; kk < 4; kk++) {
      int ch = ((kk * 4 + q) ^ rs) * 16;  // byte offset within 256B row
      int lrow = w * 16 + row16;
      short8 raw = *(const short8*)((const char*)Ps + lrow * 256 + ch);
      short8 af;
#pragma unroll
      for (int e = 0; e < 8; e++) af[e] = (short)f2bf(__expf(bf2f((u16)raw[e])));
      short8 bfr[4];
#pragma unroll
      for (int j = 0; j < 4; j++) {
        int dh = j * 16 + row16;
        bfr[j] = *(const short8*)((const char*)Vs + dh * 256 + ch);
      }
#pragma unroll
      for (int j = 0; j < 4; j++)
        acc[j] = __builtin_amdgcn_mfma_f32_16x16x32_bf16(af, bfr[j], acc[j], 0, 0, 0);
      acc[4] = __builtin_amdgcn_mfma_f32_16x16x32_bf16(af, onesf, acc[4], 0, 0, 0);
    }
  }

  // epilogue: row = l0 + w*16 + q*4 + r; col(dh) = j*16 + row16
#pragma unroll
  for (int r = 0; r < 4; r++) {
    float sum = __shfl(acc[4][r], lane & 48, 64);
    float inv = 1.0f / sum;
    int row = l0 + w * 16 + q * 4 + r;
    float* op = out + ((size_t)b * NL + row) * ND + n * NDH;
#pragma unroll
    for (int j = 0; j < 4; j++)
      op[j * 16 + row16] = acc[j][r] * inv;
  }
}

extern "C" void kernel_launch(void* const* d_in, const int* in_sizes, int n_in,
                              void* d_out, int out_size, void* d_ws, size_t ws_size,
                              hipStream_t stream) {
  (void)in_sizes; (void)n_in; (void)out_size;
  const float* x  = (const float*)d_in[0];
  const float* kI = (const float*)d_in[1];
  const float* qI = (const float*)d_in[2];
  const float* vI = (const float*)d_in[3];
  float* out = (float*)d_out;

  size_t off = 0;
  char* wsb = (char*)d_ws;
  auto alloc = [&](size_t bytes) -> char* {
    char* p = wsb + off;
    off += (bytes + 255) & ~(size_t)255;
    return p;
  };
  u16* xb = (u16*)alloc((size_t)NB * NL * ND * 2);   // bf16 x, [b][l][d]
  u16* qT = (u16*)alloc((size_t)NH * ND * ND * 2);   // q^T per head: [n][d][c]
  u16* kT = (u16*)alloc((size_t)NH * ND * ND * 2);   // k^T per head: [n][e][c]
  u16* vb = (u16*)alloc((size_t)NH * NDH * ND * 2);  // bf16 v, [n][dh][d]
  u16* MT = (u16*)alloc((size_t)NH * ND * ND * 2);   // MT[n][e][d] = M[d][e]
  size_t fixedSz = off;
  const size_t perPair = (size_t)NL * ND * 2 + (size_t)NL * NL * 2 + (size_t)NDH * NL * 2;
  int chunk = NB * NH;
  if (fixedSz + (size_t)chunk * perPair > ws_size) {
    size_t avail = ws_size > fixedSz ? ws_size - fixedSz : 0;
    chunk = (int)(avail / perPair);
    if (chunk < 1) chunk = 1;
    if (chunk > NB * NH) chunk = NB * NH;
  }
  u16* T  = (u16*)alloc((size_t)chunk * NL * ND * 2);   // [z][l][e]
  u16* Sb = (u16*)alloc((size_t)chunk * NL * NL * 2);   // [z][l][m] logits
  u16* V2 = (u16*)alloc((size_t)chunk * NDH * NL * 2);  // [z][dh][m]

  const long DD  = (long)ND * ND;
  const long LD  = (long)NL * ND;
  const long LL  = (long)NL * NL;
  const long DHD = (long)NDH * ND;
  const long DHL = (long)NDH * NL;

  {
    int n4 = NB * NL * ND / 4;
    cast_bf16_kernel<<<dim3((n4 + 255) / 256), dim3(256), 0, stream>>>(x, xb, n4);
    int n4v = NH * NDH * ND / 4;
    cast_bf16_kernel<<<dim3((n4v + 255) / 256), dim3(256), 0, stream>>>(vI, vb, n4v);
  }
  transpose_cast_kernel<<<dim3(24, 24, NH), dim3(256), 0, stream>>>(qI, qT);
  transpose_cast_kernel<<<dim3(24, 24, NH), dim3(256), 0, stream>>>(kI, kT);

  // MT[n][e][d] = sum_c kT[n][e][c] * qT[n][d][c]   (768x768, K=768)
  gemm_bt<true, 2, 2, 768, ND><<<dim3(6, 6, NH), dim3(256), 0, stream>>>(
      kT, qT, MT,
      0, DD, 0,  0, DD, 0,  0, DD, 0, 0);

  for (int p0 = 0; p0 < NB * NH; p0 += chunk) {
    int c = NB * NH - p0;
    if (c > chunk) c = chunk;
    // V2[z][dh][m] = sum_d vb[n][dh][d] * xb[b][m][d]   (64x1024, K=768), 64x64 tiles
    gemm_bt<true, 1, 1, 768, NL><<<dim3(16, 1, c), dim3(256), 0, stream>>>(
        vb, xb, V2,
        0, DHD, 0,  LD, 0, 0,  0, 0, DHL, p0);
    // T[z][l][e] = sum_d xb[b][l][d] * MT[n][e][d]   (1024x768, K=768)
    gemm_bt<true, 2, 2, 768, ND><<<dim3(6, 8, c), dim3(256), 0, stream>>>(
        xb, MT, T,
        LD, 0, 0,  0, DD, 0,  0, 0, LD, p0);
    // Sb[z][l][m] = sum_e T[z][l][e] * xb[b][m][e]   (1024x1024, K=768)
    gemm_bt<true, 2, 2, 768, NL><<<dim3(8, 8, c), dim3(256), 0, stream>>>(
        T, xb, Sb,
        0, 0, LD,  LD, 0, 0,  0, 0, LL, p0);
    // fused softmax + PV -> writes out directly
    softmax_pv_kernel<<<dim3(16, c), dim3(256), 0, stream>>>(Sb, V2, out, p0);
  }
}

// Round 8
// 310.835 us; speedup vs baseline: 1.6126x; 1.0251x over previous
//
#include <hip/hip_runtime.h>
#include <hip/hip_bf16.h>
#include <stdint.h>
#include <stddef.h>

typedef unsigned short u16;
typedef __attribute__((ext_vector_type(8))) short short8;
typedef __attribute__((ext_vector_type(4))) float f32x4;
typedef __attribute__((ext_vector_type(16))) float f32x16;

#define NB 4
#define NL 1024
#define ND 768
#define NH 12
#define NDH 64

__device__ __forceinline__ u16 f2bf(float f) {
  __hip_bfloat16 h = __float2bfloat16(f);
  return *reinterpret_cast<u16*>(&h);
}
__device__ __forceinline__ float bf2f(u16 u) {
  __hip_bfloat16 h;
  *reinterpret_cast<u16*>(&h) = u;
  return __bfloat162float(h);
}

// async global->LDS, 16B per lane. LDS dest is wave-uniform base; HW adds lane*16.
__device__ __forceinline__ void load16_to_lds(const u16* g, u16* l) {
  __builtin_amdgcn_global_load_lds(
      (__attribute__((address_space(1))) void*)(uintptr_t)g,
      (__attribute__((address_space(3))) void*)(uint32_t)(uintptr_t)l,
      16, 0, 0);
}

// ---------------- cast fp32 -> bf16 (vectorized) ----------------
__global__ __launch_bounds__(256) void cast_bf16_kernel(const float* __restrict__ in,
                                                        u16* __restrict__ out, int n4) {
  int i = blockIdx.x * 256 + threadIdx.x;
  int stride = gridDim.x * 256;
  for (; i < n4; i += stride) {
    float4 f = ((const float4*)in)[i];
    ushort4 o;
    o.x = f2bf(f.x); o.y = f2bf(f.y); o.z = f2bf(f.z); o.w = f2bf(f.w);
    ((ushort4*)out)[i] = o;
  }
}

// ---------------- transpose+cast: out[h][c][r] = in[h][r][c], 768x768 per head ----------------
__global__ __launch_bounds__(256) void transpose_cast_kernel(const float* __restrict__ in,
                                                             u16* __restrict__ out) {
  __shared__ float tile[32][33];
  int h = blockIdx.z;
  const float* src = in + (size_t)h * ND * ND;
  u16* dst = out + (size_t)h * ND * ND;
  int c0 = blockIdx.x * 32, r0 = blockIdx.y * 32;
  int tx = threadIdx.x & 31, ty = threadIdx.x >> 5;
#pragma unroll
  for (int i = 0; i < 32; i += 8)
    tile[ty + i][tx] = src[(size_t)(r0 + ty + i) * ND + c0 + tx];
  __syncthreads();
#pragma unroll
  for (int i = 0; i < 32; i += 8)
    dst[(size_t)(c0 + ty + i) * ND + r0 + tx] = f2bf(tile[tx][ty + i]);
}

// ---------------- gemm_bt: C[M,N] = A[M,K] * B[N,K]^T, bf16 in, fp32 acc ----------------
// 32x32x16 MFMA. MTILE = IM*64, NTILE = IN*64; 256 threads = 4 waves in 2x2 wave-tiles.
// BK=64 fixed. __launch_bounds__(256,4): cap registers at 128/wave so 4 blocks/CU
// co-reside (LDS 32KB x4 = 128KB fits) -> 4-deep overlap of the barrier drain.
// Register diet: single staging base pointer per matrix; u-th chunk offset is the
// compile-time constant u*32*KDIM (the XOR swizzle is invariant in u since 32%8==0).
// A-frag: m=lane&31, k=(lane>>5)*8+e. C/D: col=lane&31, row=(reg&3)+8*(reg>>2)+4*(lane>>5).
// XCD swizzle: chunk-contiguous work per XCD (id%8 == XCD on MI355X).
template <bool BF16_OUT, int IM, int IN, int KDIM, int LDC>
__global__ __launch_bounds__(256, 4) void gemm_bt(
    const u16* __restrict__ A, const u16* __restrict__ Bm, void* __restrict__ Cv,
    long sAb, long sAn, long sAz,
    long sBb, long sBn, long sBz,
    long sCb, long sCn, long sCz,
    int p0) {
  constexpr int BK = 64;
  constexpr int MTILE = IM * 64;
  constexpr int NTILE = IN * 64;
  constexpr int CPR = BK / 8;             // 8 chunks of 16B per row
  constexpr int ACH = MTILE * CPR / 256;
  constexpr int BCH = NTILE * CPR / 256;
  __shared__ __align__(16) u16 As[MTILE * BK];
  __shared__ __align__(16) u16 Bs[NTILE * BK];

  int id = blockIdx.x + gridDim.x * (blockIdx.y + gridDim.y * blockIdx.z);
  int total = gridDim.x * gridDim.y * gridDim.z;
  int xx, yy, zz;
  if ((total & 7) == 0) {
    int per = total >> 3;
    int wk = (id & 7) * per + (id >> 3);
    xx = wk % gridDim.x;
    int g2 = wk / gridDim.x;
    yy = g2 % gridDim.y;
    zz = g2 / gridDim.y;
  } else {
    xx = blockIdx.x; yy = blockIdx.y; zz = blockIdx.z;
  }

  int g = p0 + zz;
  int b = g / NH, n = g % NH;
  A  += (size_t)b * sAb + (size_t)n * sAn + (size_t)zz * sAz;
  Bm += (size_t)b * sBb + (size_t)n * sBn + (size_t)zz * sBz;
  size_t cOff = (size_t)b * sCb + (size_t)n * sCn + (size_t)zz * sCz;

  int m0 = yy * MTILE, n0 = xx * NTILE;
  int t = threadIdx.x;
  int lane = t & 63, w = t >> 6;
  int m32 = lane & 31, kg = lane >> 5;
  int wm = w >> 1, wn = w & 1;

  // single staging base per matrix (XOR swizzle; u-offsets are compile-time)
  const u16* gAb;
  const u16* gBb;
  {
    int r = t / CPR;
    int cc = (t & (CPR - 1)) ^ (r & 7);
    gAb = A + (size_t)(m0 + r) * KDIM + cc * 8;
    gBb = Bm + (size_t)(n0 + r) * KDIM + cc * 8;
  }

  f32x16 acc[IM][IN];
#pragma unroll
  for (int i = 0; i < IM; i++)
#pragma unroll
    for (int j = 0; j < IN; j++)
#pragma unroll
      for (int r = 0; r < 16; r++) acc[i][j][r] = 0.f;

#pragma unroll 1
  for (int k0 = 0; k0 < KDIM; k0 += BK) {
    __syncthreads();
#pragma unroll
    for (int u = 0; u < ACH; u++)
      load16_to_lds(gAb + (size_t)u * 32 * KDIM, &As[(size_t)(u * 256 + w * 64) * 8]);
    gAb += BK;
#pragma unroll
    for (int u = 0; u < BCH; u++)
      load16_to_lds(gBb + (size_t)u * 32 * KDIM, &Bs[(size_t)(u * 256 + w * 64) * 8]);
    gBb += BK;
    __syncthreads();

#pragma unroll
    for (int kc = 0; kc < 2; kc++) {
      short8 af[IM][2], bfr[IN][2];
#pragma unroll
      for (int i = 0; i < IM; i++) {
        int row = wm * (IM * 32) + i * 32 + m32;
#pragma unroll
        for (int h = 0; h < 2; h++) {
          int ck = (kc * 4 + h * 2 + kg) ^ (row & 7);
          af[i][h] = *(const short8*)&As[row * BK + ck * 8];
        }
      }
#pragma unroll
      for (int j = 0; j < IN; j++) {
        int row = wn * (IN * 32) + j * 32 + m32;
#pragma unroll
        for (int h = 0; h < 2; h++) {
          int ck = (kc * 4 + h * 2 + kg) ^ (row & 7);
          bfr[j][h] = *(const short8*)&Bs[row * BK + ck * 8];
        }
      }
#pragma unroll
      for (int i = 0; i < IM; i++)
#pragma unroll
        for (int j = 0; j < IN; j++) {
          acc[i][j] = __builtin_amdgcn_mfma_f32_32x32x16_bf16(af[i][0], bfr[j][0], acc[i][j], 0, 0, 0);
          acc[i][j] = __builtin_amdgcn_mfma_f32_32x32x16_bf16(af[i][1], bfr[j][1], acc[i][j], 0, 0, 0);
        }
    }
  }

  // epilogue: row = (reg&3) + 8*(reg>>2) + 4*kg; col = m32 (within 32x32 tile)
#pragma unroll
  for (int i = 0; i < IM; i++) {
#pragma unroll
    for (int j = 0; j < IN; j++) {
      int colg = n0 + wn * (IN * 32) + j * 32 + m32;
#pragma unroll
      for (int r = 0; r < 16; r++) {
        int rowg = m0 + wm * (IM * 32) + i * 32 + (r & 3) + 8 * (r >> 2) + 4 * kg;
        float vv = acc[i][j][r];
        if (BF16_OUT) {
          ((u16*)Cv)[cOff + (size_t)rowg * LDC + colg] = f2bf(vv);
        } else {
          ((float*)Cv)[cOff + (size_t)rowg * LDC + colg] = vv;
        }
      }
    }
  }
}

// ---------------- fused softmax + PV ----------------
// out[b][l][n*64+dh] = sum_m exp(Sb[z][l][m]) * V2[z][dh][m] / sum_m exp(Sb[z][l][m])
// Logits are O(1) (bf16-safe) -> no max subtraction, single pass, no rescale.
// 64-row tiles, grid (16,c) = 768 blocks (~3/CU so barrier drains overlap), LDS 32KB.
// 5th B-tile (ones in col 0) makes the MFMA compute row sums; epilogue divides.
__global__ __launch_bounds__(256) void softmax_pv_kernel(
    const u16* __restrict__ Sb, const u16* __restrict__ V2, float* __restrict__ out,
    int p0) {
  __shared__ __align__(16) u16 Ps[64 * 128];  // 16 KB
  __shared__ __align__(16) u16 Vs[64 * 128];  // 16 KB

  int id = blockIdx.x + gridDim.x * blockIdx.y;
  int total = gridDim.x * gridDim.y;
  int xx, zz;
  if ((total & 7) == 0) {
    int per = total >> 3;
    int wk = (id & 7) * per + (id >> 3);
    xx = wk & 15; zz = wk >> 4;
  } else {
    xx = blockIdx.x; zz = blockIdx.y;
  }

  int g = p0 + zz;
  int b = g / NH, n = g % NH;
  const u16* S = Sb + (size_t)zz * NL * NL;
  const u16* V = V2 + (size_t)zz * NDH * NL;

  int l0 = xx * 64;
  int t = threadIdx.x;
  int lane = t & 63, w = t >> 6;
  int row16 = lane & 15, q = lane >> 4;
  int rs = row16 & 7;

  f32x4 acc[5];
#pragma unroll
  for (int j = 0; j < 5; j++) acc[j] = (f32x4){0.f, 0.f, 0.f, 0.f};

  short8 onesf;
  {
    short val = (row16 == 0) ? (short)0x3F80 : (short)0;
#pragma unroll
    for (int e = 0; e < 8; e++) onesf[e] = val;
  }

  // per-thread staging bases (write-side swizzle cc = (c&15)^(r&7))
  const u16* ssrc[4];
  const u16* vsrc[4];
#pragma unroll
  for (int u = 0; u < 4; u++) {
    int c = u * 256 + t;
    int r = c >> 4, cc = (c & 15) ^ (r & 7);
    ssrc[u] = S + (size_t)(l0 + r) * NL + cc * 8;
    vsrc[u] = V + (size_t)r * NL + cc * 8;
  }

#pragma unroll 1
  for (int mt = 0; mt < 8; mt++) {
    int mo = mt * 128;
    __syncthreads();
#pragma unroll
    for (int u = 0; u < 4; u++)
      load16_to_lds(ssrc[u] + mo, &Ps[(size_t)(u * 256 + w * 64) * 8]);
#pragma unroll
    for (int u = 0; u < 4; u++)
      load16_to_lds(vsrc[u] + mo, &Vs[(size_t)(u * 256 + w * 64) * 8]);
    __syncthreads();

#pragma unroll
    for (int kk = 0; kk < 4; kk++) {
      int ch = ((kk * 4 + q) ^ rs) * 16;  // byte offset within 256B row
      int lrow = w * 16 + row16;
      short8 raw = *(const short8*)((const char*)Ps + lrow * 256 + ch);
      short8 af;
#pragma unroll
      for (int e = 0; e < 8; e++) af[e] = (short)f2bf(__expf(bf2f((u16)raw[e])));
      short8 bfr[4];
#pragma unroll
      for (int j = 0; j < 4; j++) {
        int dh = j * 16 + row16;
        bfr[j] = *(const short8*)((const char*)Vs + dh * 256 + ch);
      }
#pragma unroll
      for (int j = 0; j < 4; j++)
        acc[j] = __builtin_amdgcn_mfma_f32_16x16x32_bf16(af, bfr[j], acc[j], 0, 0, 0);
      acc[4] = __builtin_amdgcn_mfma_f32_16x16x32_bf16(af, onesf, acc[4], 0, 0, 0);
    }
  }

  // epilogue: row = l0 + w*16 + q*4 + r; col(dh) = j*16 + row16
#pragma unroll
  for (int r = 0; r < 4; r++) {
    float sum = __shfl(acc[4][r], lane & 48, 64);
    float inv = 1.0f / sum;
    int row = l0 + w * 16 + q * 4 + r;
    float* op = out + ((size_t)b * NL + row) * ND + n * NDH;
#pragma unroll
    for (int j = 0; j < 4; j++)
      op[j * 16 + row16] = acc[j][r] * inv;
  }
}

extern "C" void kernel_launch(void* const* d_in, const int* in_sizes, int n_in,
                              void* d_out, int out_size, void* d_ws, size_t ws_size,
                              hipStream_t stream) {
  (void)in_sizes; (void)n_in; (void)out_size;
  const float* x  = (const float*)d_in[0];
  const float* kI = (const float*)d_in[1];
  const float* qI = (const float*)d_in[2];
  const float* vI = (const float*)d_in[3];
  float* out = (float*)d_out;

  size_t off = 0;
  char* wsb = (char*)d_ws;
  auto alloc = [&](size_t bytes) -> char* {
    char* p = wsb + off;
    off += (bytes + 255) & ~(size_t)255;
    return p;
  };
  u16* xb = (u16*)alloc((size_t)NB * NL * ND * 2);   // bf16 x, [b][l][d]
  u16* qT = (u16*)alloc((size_t)NH * ND * ND * 2);   // q^T per head: [n][d][c]
  u16* kT = (u16*)alloc((size_t)NH * ND * ND * 2);   // k^T per head: [n][e][c]
  u16* vb = (u16*)alloc((size_t)NH * NDH * ND * 2);  // bf16 v, [n][dh][d]
  u16* MT = (u16*)alloc((size_t)NH * ND * ND * 2);   // MT[n][e][d] = M[d][e]
  size_t fixedSz = off;
  const size_t perPair = (size_t)NL * ND * 2 + (size_t)NL * NL * 2 + (size_t)NDH * NL * 2;
  int chunk = NB * NH;
  if (fixedSz + (size_t)chunk * perPair > ws_size) {
    size_t avail = ws_size > fixedSz ? ws_size - fixedSz : 0;
    chunk = (int)(avail / perPair);
    if (chunk < 1) chunk = 1;
    if (chunk > NB * NH) chunk = NB * NH;
  }
  u16* T  = (u16*)alloc((size_t)chunk * NL * ND * 2);   // [z][l][e]
  u16* Sb = (u16*)alloc((size_t)chunk * NL * NL * 2);   // [z][l][m] logits
  u16* V2 = (u16*)alloc((size_t)chunk * NDH * NL * 2);  // [z][dh][m]

  const long DD  = (long)ND * ND;
  const long LD  = (long)NL * ND;
  const long LL  = (long)NL * NL;
  const long DHD = (long)NDH * ND;
  const long DHL = (long)NDH * NL;

  {
    int n4 = NB * NL * ND / 4;
    cast_bf16_kernel<<<dim3((n4 + 255) / 256), dim3(256), 0, stream>>>(x, xb, n4);
    int n4v = NH * NDH * ND / 4;
    cast_bf16_kernel<<<dim3((n4v + 255) / 256), dim3(256), 0, stream>>>(vI, vb, n4v);
  }
  transpose_cast_kernel<<<dim3(24, 24, NH), dim3(256), 0, stream>>>(qI, qT);
  transpose_cast_kernel<<<dim3(24, 24, NH), dim3(256), 0, stream>>>(kI, kT);

  // MT[n][e][d] = sum_c kT[n][e][c] * qT[n][d][c]   (768x768, K=768)
  gemm_bt<true, 2, 2, 768, ND><<<dim3(6, 6, NH), dim3(256), 0, stream>>>(
      kT, qT, MT,
      0, DD, 0,  0, DD, 0,  0, DD, 0, 0);

  for (int p0 = 0; p0 < NB * NH; p0 += chunk) {
    int c = NB * NH - p0;
    if (c > chunk) c = chunk;
    // V2[z][dh][m] = sum_d vb[n][dh][d] * xb[b][m][d]   (64x1024, K=768), 64x64 tiles
    gemm_bt<true, 1, 1, 768, NL><<<dim3(16, 1, c), dim3(256), 0, stream>>>(
        vb, xb, V2,
        0, DHD, 0,  LD, 0, 0,  0, 0, DHL, p0);
    // T[z][l][e] = sum_d xb[b][l][d] * MT[n][e][d]   (1024x768, K=768)
    gemm_bt<true, 2, 2, 768, ND><<<dim3(6, 8, c), dim3(256), 0, stream>>>(
        xb, MT, T,
        LD, 0, 0,  0, DD, 0,  0, 0, LD, p0);
    // Sb[z][l][m] = sum_e T[z][l][e] * xb[b][m][e]   (1024x1024, K=768)
    gemm_bt<true, 2, 2, 768, NL><<<dim3(8, 8, c), dim3(256), 0, stream>>>(
        T, xb, Sb,
        0, 0, LD,  LD, 0, 0,  0, 0, LL, p0);
    // fused softmax + PV -> writes out directly
    softmax_pv_kernel<<<dim3(16, c), dim3(256), 0, stream>>>(Sb, V2, out, p0);
  }
}